// Round 2
// baseline (7244.155 us; speedup 1.0000x reference)
//
#include <hip/hip_runtime.h>

#define BATCH 4
#define NPTS  16384
#define CH    128
#define KNN   16

#define NCHUNK 4            // candidate-dim split per query
#define CHLEN  (NPTS / NCHUNK)   // 4096
#define QPB    128          // queries per block
#define KTILE  1024         // candidates staged per chunk per tile

// ---------------- workspace layout (bytes) ----------------
#define XT_OFF    0
#define HT_OFF    33554432
#define IDX_OFF   67108864
#define PART_OFF  71303168
#define STATS_OFF 75497472

// ---------------------------------------------------------------------------
// 1) transpose x [B,CH,N] -> xt [B,N,CH]
__global__ __launch_bounds__(256) void transpose_kernel(const float* __restrict__ x,
                                                        float* __restrict__ xt) {
    __shared__ float t[32][33];
    const int b  = blockIdx.z;
    const int c0 = blockIdx.y * 32;
    const int n0 = blockIdx.x * 32;
    const int tx = threadIdx.x, ty = threadIdx.y;   // block (32,8)
#pragma unroll
    for (int i = 0; i < 4; ++i)
        t[ty + 8 * i][tx] = x[((size_t)b * CH + c0 + ty + 8 * i) * NPTS + n0 + tx];
    __syncthreads();
#pragma unroll
    for (int i = 0; i < 4; ++i)
        xt[((size_t)b * NPTS + n0 + ty + 8 * i) * CH + c0 + tx] = t[tx][ty + 8 * i];
}

// ---------------------------------------------------------------------------
// 2) exact KNN, chunk-split for occupancy.
//    Thread = (query, chunk); each scans CHLEN candidates keeping a sorted
//    top-16 in registers (stable insertion, strict <, matches top_k ties).
//    4 sorted lists merged in LDS; lower chunk wins distance ties (= lower
//    candidate index, matching jax.lax.top_k).
__device__ __forceinline__ void insert16(float (&dq)[KNN], int (&iq)[KNN], float d, int gi) {
    float cd = d; int ci = gi;
#pragma unroll
    for (int s = KNN - 1; s >= 1; --s) {
        if (cd < dq[s - 1]) {
            dq[s] = dq[s - 1]; iq[s] = iq[s - 1];
            if (s == 1) { dq[0] = cd; iq[0] = ci; }
        } else {
            dq[s] = cd; iq[s] = ci;
            break;
        }
    }
}

__global__ __launch_bounds__(512, 4) void knn_kernel(const float* __restrict__ xyz,
                                                     int* __restrict__ idx_out) {
    __shared__ __align__(16) float smem[16 * 1024];   // 64 KB, staged tiles / merge lists
    float4* sP = (float4*)smem;                       // [NCHUNK][KTILE]

    const int b   = blockIdx.y;
    const int tid = threadIdx.x;
    const int c   = tid >> 7;        // chunk 0..3 (wave-uniform: 2 waves per chunk)
    const int ql  = tid & 127;       // local query
    const int q   = blockIdx.x * QPB + ql;
    const float* xb = xyz + (size_t)b * NPTS * 3;

    const float qx = xb[q * 3 + 0];
    const float qy = xb[q * 3 + 1];
    const float qz = xb[q * 3 + 2];

    float dq[KNN]; int iq[KNN];
#pragma unroll
    for (int s = 0; s < KNN; ++s) { dq[s] = 3.0e38f; iq[s] = 0; }
    float worst = 3.0e38f;

    const int cbase = c * CHLEN;

    for (int t0 = 0; t0 < CHLEN; t0 += KTILE) {
        __syncthreads();
        // stage NCHUNK*KTILE = 4096 points with all 512 threads
#pragma unroll
        for (int i = 0; i < (NCHUNK * KTILE) / 512; ++i) {
            const int j  = i * 512 + tid;          // 0..4095
            const int cc = j >> 10;                // which chunk's tile
            const int jj = j & (KTILE - 1);
            const float* p = xb + (size_t)(cc * CHLEN + t0 + jj) * 3;
            sP[cc * KTILE + jj] = make_float4(p[0], p[1], p[2], 0.0f);
        }
        __syncthreads();

        const float4* tile = sP + c * KTILE;
        const int gbase = cbase + t0;
        for (int j = 0; j < KTILE; j += 4) {
            const float4 p0 = tile[j + 0];
            const float4 p1 = tile[j + 1];
            const float4 p2 = tile[j + 2];
            const float4 p3 = tile[j + 3];
            float dx, dy, dz;
            dx = __fsub_rn(qx, p0.x); dy = __fsub_rn(qy, p0.y); dz = __fsub_rn(qz, p0.z);
            const float d0 = __fadd_rn(__fadd_rn(__fmul_rn(dx, dx), __fmul_rn(dy, dy)), __fmul_rn(dz, dz));
            dx = __fsub_rn(qx, p1.x); dy = __fsub_rn(qy, p1.y); dz = __fsub_rn(qz, p1.z);
            const float d1 = __fadd_rn(__fadd_rn(__fmul_rn(dx, dx), __fmul_rn(dy, dy)), __fmul_rn(dz, dz));
            dx = __fsub_rn(qx, p2.x); dy = __fsub_rn(qy, p2.y); dz = __fsub_rn(qz, p2.z);
            const float d2 = __fadd_rn(__fadd_rn(__fmul_rn(dx, dx), __fmul_rn(dy, dy)), __fmul_rn(dz, dz));
            dx = __fsub_rn(qx, p3.x); dy = __fsub_rn(qy, p3.y); dz = __fsub_rn(qz, p3.z);
            const float d3 = __fadd_rn(__fadd_rn(__fmul_rn(dx, dx), __fmul_rn(dy, dy)), __fmul_rn(dz, dz));

            if (fminf(fminf(d0, d1), fminf(d2, d3)) < worst) {
                if (d0 < worst) { insert16(dq, iq, d0, gbase + j + 0); worst = dq[KNN - 1]; }
                if (d1 < worst) { insert16(dq, iq, d1, gbase + j + 1); worst = dq[KNN - 1]; }
                if (d2 < worst) { insert16(dq, iq, d2, gbase + j + 2); worst = dq[KNN - 1]; }
                if (d3 < worst) { insert16(dq, iq, d3, gbase + j + 3); worst = dq[KNN - 1]; }
            }
        }
    }

    // dump per-chunk sorted lists into LDS, then 4-way stable merge
    __syncthreads();
    float* md = smem;                                  // [QPB][NCHUNK][16] dist
    int*   mi = (int*)(smem + QPB * NCHUNK * KNN);     // [QPB][NCHUNK][16] idx
#pragma unroll
    for (int s = 0; s < KNN; ++s) {
        md[(ql * NCHUNK + c) * KNN + s] = dq[s];
        mi[(ql * NCHUNK + c) * KNN + s] = iq[s];
    }
    __syncthreads();

    if (c == 0) {
        int p0 = 0, p1 = 0, p2 = 0, p3 = 0;
        const float* mq = md + (size_t)ql * NCHUNK * KNN;
        const int*   miq = mi + (size_t)ql * NCHUNK * KNN;
        int* op = idx_out + ((size_t)b * NPTS + q) * KNN;
#pragma unroll
        for (int s = 0; s < KNN; ++s) {
            float best = mq[0 * KNN + p0]; int bc = 0;
            float d;
            d = mq[1 * KNN + p1]; if (d < best) { best = d; bc = 1; }
            d = mq[2 * KNN + p2]; if (d < best) { best = d; bc = 2; }
            d = mq[3 * KNN + p3]; if (d < best) { best = d; bc = 3; }
            int sel;
            if (bc == 0)      { sel = miq[0 * KNN + p0]; p0++; }
            else if (bc == 1) { sel = miq[1 * KNN + p1]; p1++; }
            else if (bc == 2) { sel = miq[2 * KNN + p2]; p2++; }
            else              { sel = miq[3 * KNN + p3]; p3++; }
            op[s] = sel;
        }
    }
}

// ---------------------------------------------------------------------------
// 3) gather + Laplacian dx + 1x1 conv + relu + BN partial sums.
__global__ __launch_bounds__(128) void conv_kernel(const float* __restrict__ xt,
                                                   const int* __restrict__ idx,
                                                   const float* __restrict__ W,
                                                   const float* __restrict__ bias,
                                                   float* __restrict__ h_t,
                                                   float* __restrict__ partials) {
    __shared__ __align__(16) float dxbuf[CH];
    const int o   = threadIdx.x;
    const int blk = blockIdx.x;                  // 0..4095
    const int b   = blk / (NPTS / 16);
    const int n0  = (blk % (NPTS / 16)) * 16;

    float4 w4[CH / 4];
    const float4* wrow = (const float4*)(W + (size_t)o * CH);
#pragma unroll
    for (int i = 0; i < CH / 4; ++i) w4[i] = wrow[i];
    const float bo = bias[o];

    const float* xb = xt + (size_t)b * NPTS * CH;
    float sS = 0.0f, sQ = 0.0f;

    for (int r = 0; r < 16; ++r) {
        const int n = n0 + r;
        const int* ip = idx + ((size_t)b * NPTS + n) * KNN;
        int jj[KNN];
#pragma unroll
        for (int k = 0; k < KNN; ++k) jj[k] = ip[k];
        float va[KNN];
#pragma unroll
        for (int k = 0; k < KNN; ++k) va[k] = xb[(size_t)jj[k] * CH + o];
        const float ctr = xb[(size_t)n * CH + o];
        float acc = 0.0f;
#pragma unroll
        for (int k = 0; k < KNN; ++k) acc += va[k];
        acc -= ctr;

        dxbuf[o] = acc;
        __syncthreads();

        float h = bo;
        const float4* d4 = (const float4*)dxbuf;
#pragma unroll
        for (int cc = 0; cc < CH / 4; ++cc) {
            const float4 a = d4[cc];
            const float4 w = w4[cc];
            h = fmaf(w.x, a.x, h);
            h = fmaf(w.y, a.y, h);
            h = fmaf(w.z, a.z, h);
            h = fmaf(w.w, a.w, h);
        }
        h = fmaxf(h, 0.0f);
        h_t[((size_t)b * NPTS + n) * CH + o] = h;
        sS += h;
        sQ += h * h;
        __syncthreads();
    }

    partials[(size_t)o * 4096 + blk]        = sS;
    partials[(size_t)(CH + o) * 4096 + blk] = sQ;
}

// ---------------------------------------------------------------------------
// 4) reduce partials -> mean / rstd per channel (deterministic)
__global__ __launch_bounds__(256) void bnred_kernel(const float* __restrict__ partials,
                                                    float* __restrict__ stats) {
    const int ch = blockIdx.x;   // 0..127
    const float* pS = partials + (size_t)ch * 4096;
    const float* pQ = partials + (size_t)(CH + ch) * 4096;
    float s = 0.0f, q = 0.0f;
    for (int i = threadIdx.x; i < 4096; i += 256) { s += pS[i]; q += pQ[i]; }
#pragma unroll
    for (int off = 32; off > 0; off >>= 1) {
        s += __shfl_down(s, off);
        q += __shfl_down(q, off);
    }
    __shared__ float wsum[4][2];
    const int wid = threadIdx.x >> 6;
    if ((threadIdx.x & 63) == 0) { wsum[wid][0] = s; wsum[wid][1] = q; }
    __syncthreads();
    if (threadIdx.x == 0) {
        const float S = wsum[0][0] + wsum[1][0] + wsum[2][0] + wsum[3][0];
        const float Q = wsum[0][1] + wsum[1][1] + wsum[2][1] + wsum[3][1];
        const float inv  = 1.0f / (float)(BATCH * NPTS);
        const float mean = S * inv;
        const float var  = Q * inv - mean * mean;
        stats[ch]      = mean;
        stats[CH + ch] = rsqrtf(var + 1e-5f);
    }
}

// ---------------------------------------------------------------------------
// 5) out[b,c,n] = x + gamma*(h - mean)*rstd + beta   (h stored [B,N,CH])
__global__ __launch_bounds__(256) void final_kernel(const float* __restrict__ x,
                                                    const float* __restrict__ h_t,
                                                    const float* __restrict__ stats,
                                                    const float* __restrict__ gamma,
                                                    const float* __restrict__ beta,
                                                    float* __restrict__ out) {
    __shared__ float t[32][33];
    const int b  = blockIdx.z;
    const int o0 = blockIdx.y * 32;
    const int n0 = blockIdx.x * 32;
    const int tx = threadIdx.x, ty = threadIdx.y;   // block (32,8)
#pragma unroll
    for (int i = 0; i < 4; ++i)
        t[ty + 8 * i][tx] = h_t[((size_t)b * NPTS + n0 + ty + 8 * i) * CH + o0 + tx];
    __syncthreads();
#pragma unroll
    for (int i = 0; i < 4; ++i) {
        const int o = o0 + ty + 8 * i;
        const float mean = stats[o];
        const float rstd = stats[CH + o];
        const float g = gamma[o], be = beta[o];
        const size_t off = ((size_t)b * CH + o) * NPTS + n0 + tx;
        out[off] = x[off] + g * ((t[tx][ty + 8 * i] - mean) * rstd) + be;
    }
}

// ---------------------------------------------------------------------------
extern "C" void kernel_launch(void* const* d_in, const int* in_sizes, int n_in,
                              void* d_out, int out_size, void* d_ws, size_t ws_size,
                              hipStream_t stream) {
    const float* xyz    = (const float*)d_in[0];
    const float* x      = (const float*)d_in[1];
    const float* conv_w = (const float*)d_in[2];
    const float* conv_b = (const float*)d_in[3];
    const float* gamma  = (const float*)d_in[4];
    const float* beta   = (const float*)d_in[5];
    float* out = (float*)d_out;

    char* ws = (char*)d_ws;
    float* xt    = (float*)(ws + XT_OFF);
    float* h_t   = (float*)(ws + HT_OFF);
    int*   idx   = (int*)  (ws + IDX_OFF);
    float* part  = (float*)(ws + PART_OFF);
    float* stats = (float*)(ws + STATS_OFF);

    transpose_kernel<<<dim3(NPTS / 32, CH / 32, BATCH), dim3(32, 8), 0, stream>>>(x, xt);
    knn_kernel<<<dim3(NPTS / QPB, BATCH), dim3(512), 0, stream>>>(xyz, idx);
    conv_kernel<<<dim3(BATCH * NPTS / 16), dim3(128), 0, stream>>>(xt, idx, conv_w, conv_b, h_t, part);
    bnred_kernel<<<dim3(CH), dim3(256), 0, stream>>>(part, stats);
    final_kernel<<<dim3(NPTS / 32, CH / 32, BATCH), dim3(32, 8), 0, stream>>>(x, h_t, stats, gamma, beta, out);
}

// Round 3
// 3349.233 us; speedup vs baseline: 2.1629x; 2.1629x over previous
//
#include <hip/hip_runtime.h>

#define BATCH 4
#define NPTS  16384
#define CH    128
#define KNN   16

// ---- spatial grid ----
#define G      64
#define GRID3  (G * G * G)          // 262144 cells per batch
#define GW     0.25f
#define GINVW  4.0f
#define GORIG  (-8.0f)

// ---------------- workspace layout (bytes) ----------------
// xt    : [B][N][CH] float     off 0           33,554,432
// grid region (reused later by h_t):
//   counts : [B][G^3] int      off 33554432     4,194,304
//   cursor : [B][G^3] int      off 37748736     4,194,304
//   offs   : [B][G^3] int      off 41943040     4,194,304
//   spts   : [B][N] float4     off 46137344     1,048,576
// h_t   : [B][N][CH] float     off 33554432    33,554,432  (written after knn done)
// idx   : [B][N][16] int       off 67108864     4,194,304
// part  : [256][4096] float    off 71303168     4,194,304
// stats : [256] float          off 75497472         1,024
#define XT_OFF    0
#define HT_OFF    33554432
#define CNT_OFF   33554432
#define CUR_OFF   37748736
#define OFFS_OFF  41943040
#define SPTS_OFF  46137344
#define IDX_OFF   67108864
#define PART_OFF  71303168
#define STATS_OFF 75497472

__device__ __forceinline__ int cell1(float v) {
    int c = (int)floorf((v - GORIG) * GINVW);
    return min(G - 1, max(0, c));
}

// ---------------------------------------------------------------------------
// 0) zero grid counters
__global__ __launch_bounds__(256) void zero_kernel(int* __restrict__ p, int n) {
    int i = blockIdx.x * 256 + threadIdx.x;
    int stride = gridDim.x * 256;
    for (; i < n; i += stride) p[i] = 0;
}

// ---------------------------------------------------------------------------
// 1) transpose x [B,CH,N] -> xt [B,N,CH]
__global__ __launch_bounds__(256) void transpose_kernel(const float* __restrict__ x,
                                                        float* __restrict__ xt) {
    __shared__ float t[32][33];
    const int b  = blockIdx.z;
    const int c0 = blockIdx.y * 32;
    const int n0 = blockIdx.x * 32;
    const int tx = threadIdx.x, ty = threadIdx.y;   // block (32,8)
#pragma unroll
    for (int i = 0; i < 4; ++i)
        t[ty + 8 * i][tx] = x[((size_t)b * CH + c0 + ty + 8 * i) * NPTS + n0 + tx];
    __syncthreads();
#pragma unroll
    for (int i = 0; i < 4; ++i)
        xt[((size_t)b * NPTS + n0 + ty + 8 * i) * CH + c0 + tx] = t[tx][ty + 8 * i];
}

// ---------------------------------------------------------------------------
// 2a) count points per cell
__global__ __launch_bounds__(256) void count_kernel(const float* __restrict__ xyz,
                                                    int* __restrict__ counts) {
    const int b = blockIdx.y;
    const int i = blockIdx.x * 256 + threadIdx.x;
    const float* p = xyz + ((size_t)b * NPTS + i) * 3;
    const int c = (cell1(p[2]) * G + cell1(p[1])) * G + cell1(p[0]);
    atomicAdd(&counts[(size_t)b * GRID3 + c], 1);
}

// 2b) exclusive scan per batch (one 1024-thread block per batch)
__global__ __launch_bounds__(1024) void scan_kernel(const int* __restrict__ counts,
                                                    int* __restrict__ offs) {
    __shared__ int sd[1024];
    const int b = blockIdx.x;
    const int* c = counts + (size_t)b * GRID3;
    int* o = offs + (size_t)b * GRID3;
    int carry = 0;
    for (int it = 0; it < GRID3 / 1024; ++it) {
        const int i = it * 1024 + threadIdx.x;
        const int v = c[i];
        sd[threadIdx.x] = v;
        __syncthreads();
        for (int off = 1; off < 1024; off <<= 1) {
            int t = (threadIdx.x >= off) ? sd[threadIdx.x - off] : 0;
            __syncthreads();
            sd[threadIdx.x] += t;
            __syncthreads();
        }
        const int incl = sd[threadIdx.x];
        const int tot  = sd[1023];
        o[i] = incl - v + carry;
        carry += tot;
        __syncthreads();
    }
}

// 2c) scatter points into cell-sorted order, original idx in .w
__global__ __launch_bounds__(256) void scatter_kernel(const float* __restrict__ xyz,
                                                      const int* __restrict__ offs,
                                                      int* __restrict__ cursor,
                                                      float4* __restrict__ spts) {
    const int b = blockIdx.y;
    const int i = blockIdx.x * 256 + threadIdx.x;
    const float* p = xyz + ((size_t)b * NPTS + i) * 3;
    const float x = p[0], y = p[1], z = p[2];
    const int c = (cell1(z) * G + cell1(y)) * G + cell1(x);
    const int pos = offs[(size_t)b * GRID3 + c] + atomicAdd(&cursor[(size_t)b * GRID3 + c], 1);
    spts[(size_t)b * NPTS + pos] = make_float4(x, y, z, __int_as_float(i));
}

// ---------------------------------------------------------------------------
// 2d) exact KNN via expanding-ring grid search.
//     Selection is by lexicographic (d, original_idx) -> identical set and
//     order as jax.lax.top_k(-d) regardless of candidate traversal order.
//     Distance math uses the exact same rn ops as the reference association.
__global__ __launch_bounds__(256) void knn_grid_kernel(const float4* __restrict__ spts,
                                                       const int* __restrict__ counts,
                                                       const int* __restrict__ offs,
                                                       int* __restrict__ idx_out) {
    const int b = blockIdx.y;
    const int s = blockIdx.x * 256 + threadIdx.x;
    const float4 P = spts[(size_t)b * NPTS + s];
    const float qx = P.x, qy = P.y, qz = P.z;
    const int qi = __float_as_int(P.w);
    const int cx = cell1(qx), cy = cell1(qy), cz = cell1(qz);
    const int* cnt = counts + (size_t)b * GRID3;
    const int* off = offs + (size_t)b * GRID3;
    const float4* pts = spts + (size_t)b * NPTS;

    float dq[KNN]; int iq[KNN];
#pragma unroll
    for (int t = 0; t < KNN; ++t) { dq[t] = 3.0e38f; iq[t] = 0x7fffffff; }

    for (int R = 0; R < G; ++R) {
        if (R > 0) {
            // processed box = rings 0..R-1 -> cells [c-(R-1), c+(R-1)] (clipped)
            const int rm = R - 1;
            float dmin = 3.0e38f;
            bool any = false;
            if (cx - rm > 0)     { dmin = fminf(dmin, qx - (GORIG + (cx - rm) * GW)); any = true; }
            if (cx + rm < G - 1) { dmin = fminf(dmin, (GORIG + (cx + rm + 1) * GW) - qx); any = true; }
            if (cy - rm > 0)     { dmin = fminf(dmin, qy - (GORIG + (cy - rm) * GW)); any = true; }
            if (cy + rm < G - 1) { dmin = fminf(dmin, (GORIG + (cy + rm + 1) * GW) - qy); any = true; }
            if (cz - rm > 0)     { dmin = fminf(dmin, qz - (GORIG + (cz - rm) * GW)); any = true; }
            if (cz + rm < G - 1) { dmin = fminf(dmin, (GORIG + (cz + rm + 1) * GW) - qz); any = true; }
            if (!any) break;                       // whole grid processed
            dmin = fmaxf(dmin, 0.0f);
            if (dq[KNN - 1] < dmin * dmin * (1.0f - 1e-5f)) break;
        }
        const int z0 = max(0, cz - R), z1 = min(G - 1, cz + R);
        const int y0 = max(0, cy - R), y1 = min(G - 1, cy + R);
        const int x0 = max(0, cx - R), x1 = min(G - 1, cx + R);
        for (int z = z0; z <= z1; ++z) {
            const int az = (z > cz) ? (z - cz) : (cz - z);
            const float lz = GORIG + z * GW;
            const float dzc = fmaxf(fmaxf(lz - qz, qz - (lz + GW)), 0.0f);
            for (int y = y0; y <= y1; ++y) {
                const int ay = (y > cy) ? (y - cy) : (cy - y);
                const float ly = GORIG + y * GW;
                const float dyc = fmaxf(fmaxf(ly - qy, qy - (ly + GW)), 0.0f);
                const bool edgeZY = (az == R) || (ay == R);
                const float dzy = dzc * dzc + dyc * dyc;
                for (int x = x0; x <= x1; ++x) {
                    const int ax = (x > cx) ? (x - cx) : (cx - x);
                    if (!edgeZY && ax != R) continue;      // shell cells only
                    const float lx = GORIG + x * GW;
                    const float dxc = fmaxf(fmaxf(lx - qx, qx - (lx + GW)), 0.0f);
                    const float cmin = dzy + dxc * dxc;
                    if (cmin * (1.0f - 1e-5f) > dq[KNN - 1]) continue;  // cell too far
                    const int cid = (z * G + y) * G + x;
                    const int st = off[cid];
                    const int en = st + cnt[cid];
                    for (int j = st; j < en; ++j) {
                        const float4 pp = pts[j];
                        const float ddx = __fsub_rn(qx, pp.x);
                        const float ddy = __fsub_rn(qy, pp.y);
                        const float ddz = __fsub_rn(qz, pp.z);
                        const float d = __fadd_rn(__fadd_rn(__fmul_rn(ddx, ddx), __fmul_rn(ddy, ddy)),
                                                  __fmul_rn(ddz, ddz));
                        const int oi = __float_as_int(pp.w);
                        if (d < dq[KNN - 1] || (d == dq[KNN - 1] && oi < iq[KNN - 1])) {
                            float cd = d; int ci = oi;
#pragma unroll
                            for (int t2 = KNN - 1; t2 >= 1; --t2) {
                                const bool lt = (cd < dq[t2 - 1]) ||
                                                (cd == dq[t2 - 1] && ci < iq[t2 - 1]);
                                if (lt) {
                                    dq[t2] = dq[t2 - 1]; iq[t2] = iq[t2 - 1];
                                    if (t2 == 1) { dq[0] = cd; iq[0] = ci; }
                                } else {
                                    dq[t2] = cd; iq[t2] = ci;
                                    break;
                                }
                            }
                        }
                    }
                }
            }
        }
    }

    int* op = idx_out + ((size_t)b * NPTS + qi) * KNN;
#pragma unroll
    for (int t = 0; t < KNN; ++t) op[t] = iq[t];
}

// ---------------------------------------------------------------------------
// 3) gather + Laplacian dx + 1x1 conv + relu + BN partial sums.
__global__ __launch_bounds__(128) void conv_kernel(const float* __restrict__ xt,
                                                   const int* __restrict__ idx,
                                                   const float* __restrict__ W,
                                                   const float* __restrict__ bias,
                                                   float* __restrict__ h_t,
                                                   float* __restrict__ partials) {
    __shared__ __align__(16) float dxbuf[CH];
    const int o   = threadIdx.x;
    const int blk = blockIdx.x;                  // 0..4095
    const int b   = blk / (NPTS / 16);
    const int n0  = (blk % (NPTS / 16)) * 16;

    float4 w4[CH / 4];
    const float4* wrow = (const float4*)(W + (size_t)o * CH);
#pragma unroll
    for (int i = 0; i < CH / 4; ++i) w4[i] = wrow[i];
    const float bo = bias[o];

    const float* xb = xt + (size_t)b * NPTS * CH;
    float sS = 0.0f, sQ = 0.0f;

    for (int r = 0; r < 16; ++r) {
        const int n = n0 + r;
        const int* ip = idx + ((size_t)b * NPTS + n) * KNN;
        int jj[KNN];
#pragma unroll
        for (int k = 0; k < KNN; ++k) jj[k] = ip[k];
        float va[KNN];
#pragma unroll
        for (int k = 0; k < KNN; ++k) va[k] = xb[(size_t)jj[k] * CH + o];
        const float ctr = xb[(size_t)n * CH + o];
        float acc = 0.0f;
#pragma unroll
        for (int k = 0; k < KNN; ++k) acc += va[k];
        acc -= ctr;

        dxbuf[o] = acc;
        __syncthreads();

        float h = bo;
        const float4* d4 = (const float4*)dxbuf;
#pragma unroll
        for (int cc = 0; cc < CH / 4; ++cc) {
            const float4 a = d4[cc];
            const float4 w = w4[cc];
            h = fmaf(w.x, a.x, h);
            h = fmaf(w.y, a.y, h);
            h = fmaf(w.z, a.z, h);
            h = fmaf(w.w, a.w, h);
        }
        h = fmaxf(h, 0.0f);
        h_t[((size_t)b * NPTS + n) * CH + o] = h;
        sS += h;
        sQ += h * h;
        __syncthreads();
    }

    partials[(size_t)o * 4096 + blk]        = sS;
    partials[(size_t)(CH + o) * 4096 + blk] = sQ;
}

// ---------------------------------------------------------------------------
// 4) reduce partials -> mean / rstd per channel (deterministic)
__global__ __launch_bounds__(256) void bnred_kernel(const float* __restrict__ partials,
                                                    float* __restrict__ stats) {
    const int ch = blockIdx.x;   // 0..127
    const float* pS = partials + (size_t)ch * 4096;
    const float* pQ = partials + (size_t)(CH + ch) * 4096;
    float s = 0.0f, q = 0.0f;
    for (int i = threadIdx.x; i < 4096; i += 256) { s += pS[i]; q += pQ[i]; }
#pragma unroll
    for (int off = 32; off > 0; off >>= 1) {
        s += __shfl_down(s, off);
        q += __shfl_down(q, off);
    }
    __shared__ float wsum[4][2];
    const int wid = threadIdx.x >> 6;
    if ((threadIdx.x & 63) == 0) { wsum[wid][0] = s; wsum[wid][1] = q; }
    __syncthreads();
    if (threadIdx.x == 0) {
        const float S = wsum[0][0] + wsum[1][0] + wsum[2][0] + wsum[3][0];
        const float Q = wsum[0][1] + wsum[1][1] + wsum[2][1] + wsum[3][1];
        const float inv  = 1.0f / (float)(BATCH * NPTS);
        const float mean = S * inv;
        const float var  = Q * inv - mean * mean;
        stats[ch]      = mean;
        stats[CH + ch] = rsqrtf(var + 1e-5f);
    }
}

// ---------------------------------------------------------------------------
// 5) out[b,c,n] = x + gamma*(h - mean)*rstd + beta   (h stored [B,N,CH])
__global__ __launch_bounds__(256) void final_kernel(const float* __restrict__ x,
                                                    const float* __restrict__ h_t,
                                                    const float* __restrict__ stats,
                                                    const float* __restrict__ gamma,
                                                    const float* __restrict__ beta,
                                                    float* __restrict__ out) {
    __shared__ float t[32][33];
    const int b  = blockIdx.z;
    const int o0 = blockIdx.y * 32;
    const int n0 = blockIdx.x * 32;
    const int tx = threadIdx.x, ty = threadIdx.y;   // block (32,8)
#pragma unroll
    for (int i = 0; i < 4; ++i)
        t[ty + 8 * i][tx] = h_t[((size_t)b * NPTS + n0 + ty + 8 * i) * CH + o0 + tx];
    __syncthreads();
#pragma unroll
    for (int i = 0; i < 4; ++i) {
        const int o = o0 + ty + 8 * i;
        const float mean = stats[o];
        const float rstd = stats[CH + o];
        const float g = gamma[o], be = beta[o];
        const size_t offp = ((size_t)b * CH + o) * NPTS + n0 + tx;
        out[offp] = x[offp] + g * ((t[tx][ty + 8 * i] - mean) * rstd) + be;
    }
}

// ---------------------------------------------------------------------------
extern "C" void kernel_launch(void* const* d_in, const int* in_sizes, int n_in,
                              void* d_out, int out_size, void* d_ws, size_t ws_size,
                              hipStream_t stream) {
    const float* xyz    = (const float*)d_in[0];
    const float* x      = (const float*)d_in[1];
    const float* conv_w = (const float*)d_in[2];
    const float* conv_b = (const float*)d_in[3];
    const float* gamma  = (const float*)d_in[4];
    const float* beta   = (const float*)d_in[5];
    float* out = (float*)d_out;

    char* ws = (char*)d_ws;
    float*  xt     = (float*)(ws + XT_OFF);
    int*    counts = (int*)  (ws + CNT_OFF);
    int*    cursor = (int*)  (ws + CUR_OFF);
    int*    offs   = (int*)  (ws + OFFS_OFF);
    float4* spts   = (float4*)(ws + SPTS_OFF);
    float*  h_t    = (float*)(ws + HT_OFF);
    int*    idx    = (int*)  (ws + IDX_OFF);
    float*  part   = (float*)(ws + PART_OFF);
    float*  stats  = (float*)(ws + STATS_OFF);

    // feature transpose (independent of grid work)
    transpose_kernel<<<dim3(NPTS / 32, CH / 32, BATCH), dim3(32, 8), 0, stream>>>(x, xt);

    // grid build
    zero_kernel<<<dim3(2048), dim3(256), 0, stream>>>(counts, 2 * BATCH * GRID3); // counts+cursor (adjacent)
    count_kernel<<<dim3(NPTS / 256, BATCH), dim3(256), 0, stream>>>(xyz, counts);
    scan_kernel<<<dim3(BATCH), dim3(1024), 0, stream>>>(counts, offs);
    scatter_kernel<<<dim3(NPTS / 256, BATCH), dim3(256), 0, stream>>>(xyz, offs, cursor, spts);

    // exact knn
    knn_grid_kernel<<<dim3(NPTS / 256, BATCH), dim3(256), 0, stream>>>(spts, counts, offs, idx);

    // gather + conv + relu + partial BN sums (overwrites grid region with h_t)
    conv_kernel<<<dim3(BATCH * NPTS / 16), dim3(128), 0, stream>>>(xt, idx, conv_w, conv_b, h_t, part);
    bnred_kernel<<<dim3(CH), dim3(256), 0, stream>>>(part, stats);
    final_kernel<<<dim3(NPTS / 32, CH / 32, BATCH), dim3(32, 8), 0, stream>>>(x, h_t, stats, gamma, beta, out);
}

// Round 4
// 804.253 us; speedup vs baseline: 9.0073x; 4.1644x over previous
//
#include <hip/hip_runtime.h>

#define BATCH 4
#define NPTS  16384
#define CH    128
#define KNN   16

// ---- spatial grid ----
#define G      64
#define GRID3  (G * G * G)          // 262144 cells per batch (= 2^18)
#define GW     0.25f
#define GINVW  4.0f
#define GORIG  (-8.0f)
#define OCCW   (GRID3 / 32)         // 8192 occupancy words per batch

// ---------------- workspace layout (bytes) ----------------
// xt    : [B][N][CH] float     off 0           33,554,432
// grid region (reused later by h_t, written only after knn done):
//   counts : [B][G^3] int      off 33554432     4,194,304
//   cursor : [B][G^3] int      off 37748736     4,194,304
//   hdr    : [B][G^3] int2     off 41943040     8,388,608
//   occ    : [B][G^3/32] uint  off 50331648       131,072
//   spts   : [B][N] float4     off 50462720     1,048,576
//   gctr   : [B] int           off 51511296            16
// idx   : [B][N][16] int       off 67108864     4,194,304
// part  : [256][4096] float    off 71303168     4,194,304
// stats : [256] float          off 75497472         1,024
#define XT_OFF    0
#define HT_OFF    33554432
#define CNT_OFF   33554432
#define CUR_OFF   37748736
#define HDR_OFF   41943040
#define OCC_OFF   50331648
#define SPTS_OFF  50462720
#define GCTR_OFF  51511296
#define IDX_OFF   67108864
#define PART_OFF  71303168
#define STATS_OFF 75497472

__device__ __forceinline__ int cell1(float v) {
    int c = (int)floorf((v - GORIG) * GINVW);
    return min(G - 1, max(0, c));
}

// ---------------------------------------------------------------------------
// 0) zero grid counters (counts+cursor contiguous) and per-batch allocators
__global__ __launch_bounds__(256) void zero_kernel(int* __restrict__ p, int n,
                                                   int* __restrict__ gctr) {
    int i = blockIdx.x * 256 + threadIdx.x;
    if (i < BATCH) gctr[i] = 0;
    const int stride = gridDim.x * 256;
    for (; i < n; i += stride) p[i] = 0;
}

// ---------------------------------------------------------------------------
// 1) transpose x [B,CH,N] -> xt [B,N,CH]
__global__ __launch_bounds__(256) void transpose_kernel(const float* __restrict__ x,
                                                        float* __restrict__ xt) {
    __shared__ float t[32][33];
    const int b  = blockIdx.z;
    const int c0 = blockIdx.y * 32;
    const int n0 = blockIdx.x * 32;
    const int tx = threadIdx.x, ty = threadIdx.y;   // block (32,8)
#pragma unroll
    for (int i = 0; i < 4; ++i)
        t[ty + 8 * i][tx] = x[((size_t)b * CH + c0 + ty + 8 * i) * NPTS + n0 + tx];
    __syncthreads();
#pragma unroll
    for (int i = 0; i < 4; ++i)
        xt[((size_t)b * NPTS + n0 + ty + 8 * i) * CH + c0 + tx] = t[tx][ty + 8 * i];
}

// ---------------------------------------------------------------------------
// 2a) count points per cell
__global__ __launch_bounds__(256) void count_kernel(const float* __restrict__ xyz,
                                                    int* __restrict__ counts) {
    const int b = blockIdx.y;
    const int i = blockIdx.x * 256 + threadIdx.x;
    const float* p = xyz + ((size_t)b * NPTS + i) * 3;
    const int c = (cell1(p[2]) * G + cell1(p[1])) * G + cell1(p[0]);
    atomicAdd(&counts[(size_t)b * GRID3 + c], 1);
}

// 2b) per-cell (start,count) headers + occupancy bitmask via wave-aggregated
//     atomic allocation. Cell start order is nondeterministic, but the final
//     knn selection is lexicographic in (d, original_idx) -> output exact.
__global__ __launch_bounds__(256) void cellhdr_kernel(const int* __restrict__ counts,
                                                      int2* __restrict__ hdr,
                                                      unsigned int* __restrict__ occ,
                                                      int* __restrict__ gctr) {
    const int cid  = blockIdx.x * 256 + threadIdx.x;   // 0 .. B*GRID3-1
    const int b    = cid >> 18;
    const int lane = threadIdx.x & 63;
    const int c    = counts[cid];

    // wave-wide inclusive scan of c
    int incl = c;
#pragma unroll
    for (int off = 1; off < 64; off <<= 1) {
        int t = __shfl_up(incl, off);
        if (lane >= off) incl += t;
    }
    const int excl = incl - c;
    const int tot  = __shfl(incl, 63);

    const unsigned long long ball = __ballot(c > 0);
    if (lane == 0) {
        const int w = cid >> 5;     // global word index (= b*OCCW + local)
        occ[w]     = (unsigned int)ball;
        occ[w + 1] = (unsigned int)(ball >> 32);
    }

    int base = 0;
    if (lane == 63) base = atomicAdd(&gctr[b], tot);
    base = __shfl(base, 63);

    if (c > 0) hdr[cid] = make_int2(base + excl, c);
}

// 2c) scatter points into cell-grouped order, original idx in .w
__global__ __launch_bounds__(256) void scatter_kernel(const float* __restrict__ xyz,
                                                      const int2* __restrict__ hdr,
                                                      int* __restrict__ cursor,
                                                      float4* __restrict__ spts) {
    const int b = blockIdx.y;
    const int i = blockIdx.x * 256 + threadIdx.x;
    const float* p = xyz + ((size_t)b * NPTS + i) * 3;
    const float x = p[0], y = p[1], z = p[2];
    const int c = (cell1(z) * G + cell1(y)) * G + cell1(x);
    const int pos = hdr[(size_t)b * GRID3 + c].x + atomicAdd(&cursor[(size_t)b * GRID3 + c], 1);
    spts[(size_t)b * NPTS + pos] = make_float4(x, y, z, __int_as_float(i));
}

// ---------------------------------------------------------------------------
// 2d) exact KNN via expanding rings with an LDS occupancy bitmask.
//     Empty cells cost ~1 bit; occupied cells one int2 header load.
__global__ __launch_bounds__(256) void knn_grid_kernel(const float4* __restrict__ spts,
                                                       const int2* __restrict__ hdr,
                                                       const unsigned int* __restrict__ occ,
                                                       int* __restrict__ idx_out) {
    __shared__ unsigned int socc[OCCW];    // 32 KB: this batch's occupancy bits
    const int b   = blockIdx.y;
    const int tid = threadIdx.x;
    for (int i = tid; i < OCCW; i += 256) socc[i] = occ[(size_t)b * OCCW + i];
    __syncthreads();

    const int s = blockIdx.x * 256 + tid;
    const float4 P = spts[(size_t)b * NPTS + s];
    const float qx = P.x, qy = P.y, qz = P.z;
    const int qi = __float_as_int(P.w);
    const int cx = cell1(qx), cy = cell1(qy), cz = cell1(qz);
    const int2* hb = hdr + (size_t)b * GRID3;
    const float4* pts = spts + (size_t)b * NPTS;

    float dq[KNN]; int iq[KNN];
#pragma unroll
    for (int t = 0; t < KNN; ++t) { dq[t] = 3.0e38f; iq[t] = 0x7fffffff; }

    for (int R = 0; R < G; ++R) {
        if (R > 0) {
            const int rm = R - 1;
            float dmin = 3.0e38f;
            bool any = false;
            if (cx - rm > 0)     { dmin = fminf(dmin, qx - (GORIG + (cx - rm) * GW)); any = true; }
            if (cx + rm < G - 1) { dmin = fminf(dmin, (GORIG + (cx + rm + 1) * GW) - qx); any = true; }
            if (cy - rm > 0)     { dmin = fminf(dmin, qy - (GORIG + (cy - rm) * GW)); any = true; }
            if (cy + rm < G - 1) { dmin = fminf(dmin, (GORIG + (cy + rm + 1) * GW) - qy); any = true; }
            if (cz - rm > 0)     { dmin = fminf(dmin, qz - (GORIG + (cz - rm) * GW)); any = true; }
            if (cz + rm < G - 1) { dmin = fminf(dmin, (GORIG + (cz + rm + 1) * GW) - qz); any = true; }
            if (!any) break;
            dmin = fmaxf(dmin, 0.0f);
            if (dq[KNN - 1] < dmin * dmin * (1.0f - 1e-5f)) break;
        }
        const int z0 = max(0, cz - R), z1 = min(G - 1, cz + R);
        const int y0 = max(0, cy - R), y1 = min(G - 1, cy + R);
        const int x0 = max(0, cx - R), x1 = min(G - 1, cx + R);
        for (int z = z0; z <= z1; ++z) {
            const int az = (z > cz) ? (z - cz) : (cz - z);
            const float lz = GORIG + z * GW;
            const float dzc = fmaxf(fmaxf(lz - qz, qz - (lz + GW)), 0.0f);
            for (int y = y0; y <= y1; ++y) {
                const int ay = (y > cy) ? (y - cy) : (cy - y);
                const float ly = GORIG + y * GW;
                const float dyc = fmaxf(fmaxf(ly - qy, qy - (ly + GW)), 0.0f);
                const float dzy = dzc * dzc + dyc * dyc;
                const int row = z * G + y;           // row base cell = row*64

                // eligible-x mask for this row of the shell
                unsigned long long m;
                if (az == R || ay == R) {
                    m = (~0ull >> (63 - (x1 - x0))) << x0;       // full face row
                } else {
                    m = 0ull;
                    if (cx - R >= 0) m |= 1ull << (cx - R);
                    if (cx + R < G)  m |= 1ull << (cx + R);
                }
                m &= (unsigned long long)socc[row * 2] |
                     ((unsigned long long)socc[row * 2 + 1] << 32);

                while (m) {
                    const int x = __ffsll(m) - 1;
                    m &= m - 1;
                    const float lx = GORIG + x * GW;
                    const float dxc = fmaxf(fmaxf(lx - qx, qx - (lx + GW)), 0.0f);
                    const float cmin = dzy + dxc * dxc;
                    if (cmin * (1.0f - 1e-5f) > dq[KNN - 1]) continue;
                    const int2 hc = hb[row * G + x];
                    const int en = hc.x + hc.y;
                    for (int j = hc.x; j < en; ++j) {
                        const float4 pp = pts[j];
                        const float ddx = __fsub_rn(qx, pp.x);
                        const float ddy = __fsub_rn(qy, pp.y);
                        const float ddz = __fsub_rn(qz, pp.z);
                        const float d = __fadd_rn(__fadd_rn(__fmul_rn(ddx, ddx), __fmul_rn(ddy, ddy)),
                                                  __fmul_rn(ddz, ddz));
                        const int oi = __float_as_int(pp.w);
                        if (d < dq[KNN - 1] || (d == dq[KNN - 1] && oi < iq[KNN - 1])) {
                            float cd = d; int ci = oi;
#pragma unroll
                            for (int t2 = KNN - 1; t2 >= 1; --t2) {
                                const bool lt = (cd < dq[t2 - 1]) ||
                                                (cd == dq[t2 - 1] && ci < iq[t2 - 1]);
                                if (lt) {
                                    dq[t2] = dq[t2 - 1]; iq[t2] = iq[t2 - 1];
                                    if (t2 == 1) { dq[0] = cd; iq[0] = ci; }
                                } else {
                                    dq[t2] = cd; iq[t2] = ci;
                                    break;
                                }
                            }
                        }
                    }
                }
            }
        }
    }

    int* op = idx_out + ((size_t)b * NPTS + qi) * KNN;
#pragma unroll
    for (int t = 0; t < KNN; ++t) op[t] = iq[t];
}

// ---------------------------------------------------------------------------
// 3) gather + Laplacian dx + 1x1 conv + relu + BN partial sums.
__global__ __launch_bounds__(128) void conv_kernel(const float* __restrict__ xt,
                                                   const int* __restrict__ idx,
                                                   const float* __restrict__ W,
                                                   const float* __restrict__ bias,
                                                   float* __restrict__ h_t,
                                                   float* __restrict__ partials) {
    __shared__ __align__(16) float dxbuf[CH];
    const int o   = threadIdx.x;
    const int blk = blockIdx.x;                  // 0..4095
    const int b   = blk / (NPTS / 16);
    const int n0  = (blk % (NPTS / 16)) * 16;

    float4 w4[CH / 4];
    const float4* wrow = (const float4*)(W + (size_t)o * CH);
#pragma unroll
    for (int i = 0; i < CH / 4; ++i) w4[i] = wrow[i];
    const float bo = bias[o];

    const float* xb = xt + (size_t)b * NPTS * CH;
    float sS = 0.0f, sQ = 0.0f;

    for (int r = 0; r < 16; ++r) {
        const int n = n0 + r;
        const int* ip = idx + ((size_t)b * NPTS + n) * KNN;
        int jj[KNN];
#pragma unroll
        for (int k = 0; k < KNN; ++k) jj[k] = ip[k];
        float va[KNN];
#pragma unroll
        for (int k = 0; k < KNN; ++k) va[k] = xb[(size_t)jj[k] * CH + o];
        const float ctr = xb[(size_t)n * CH + o];
        float acc = 0.0f;
#pragma unroll
        for (int k = 0; k < KNN; ++k) acc += va[k];
        acc -= ctr;

        dxbuf[o] = acc;
        __syncthreads();

        float h = bo;
        const float4* d4 = (const float4*)dxbuf;
#pragma unroll
        for (int cc = 0; cc < CH / 4; ++cc) {
            const float4 a = d4[cc];
            const float4 w = w4[cc];
            h = fmaf(w.x, a.x, h);
            h = fmaf(w.y, a.y, h);
            h = fmaf(w.z, a.z, h);
            h = fmaf(w.w, a.w, h);
        }
        h = fmaxf(h, 0.0f);
        h_t[((size_t)b * NPTS + n) * CH + o] = h;
        sS += h;
        sQ += h * h;
        __syncthreads();
    }

    partials[(size_t)o * 4096 + blk]        = sS;
    partials[(size_t)(CH + o) * 4096 + blk] = sQ;
}

// ---------------------------------------------------------------------------
// 4) reduce partials -> mean / rstd per channel (deterministic)
__global__ __launch_bounds__(256) void bnred_kernel(const float* __restrict__ partials,
                                                    float* __restrict__ stats) {
    const int ch = blockIdx.x;   // 0..127
    const float* pS = partials + (size_t)ch * 4096;
    const float* pQ = partials + (size_t)(CH + ch) * 4096;
    float s = 0.0f, q = 0.0f;
    for (int i = threadIdx.x; i < 4096; i += 256) { s += pS[i]; q += pQ[i]; }
#pragma unroll
    for (int off = 32; off > 0; off >>= 1) {
        s += __shfl_down(s, off);
        q += __shfl_down(q, off);
    }
    __shared__ float wsum[4][2];
    const int wid = threadIdx.x >> 6;
    if ((threadIdx.x & 63) == 0) { wsum[wid][0] = s; wsum[wid][1] = q; }
    __syncthreads();
    if (threadIdx.x == 0) {
        const float S = wsum[0][0] + wsum[1][0] + wsum[2][0] + wsum[3][0];
        const float Q = wsum[0][1] + wsum[1][1] + wsum[2][1] + wsum[3][1];
        const float inv  = 1.0f / (float)(BATCH * NPTS);
        const float mean = S * inv;
        const float var  = Q * inv - mean * mean;
        stats[ch]      = mean;
        stats[CH + ch] = rsqrtf(var + 1e-5f);
    }
}

// ---------------------------------------------------------------------------
// 5) out[b,c,n] = x + gamma*(h - mean)*rstd + beta   (h stored [B,N,CH])
__global__ __launch_bounds__(256) void final_kernel(const float* __restrict__ x,
                                                    const float* __restrict__ h_t,
                                                    const float* __restrict__ stats,
                                                    const float* __restrict__ gamma,
                                                    const float* __restrict__ beta,
                                                    float* __restrict__ out) {
    __shared__ float t[32][33];
    const int b  = blockIdx.z;
    const int o0 = blockIdx.y * 32;
    const int n0 = blockIdx.x * 32;
    const int tx = threadIdx.x, ty = threadIdx.y;   // block (32,8)
#pragma unroll
    for (int i = 0; i < 4; ++i)
        t[ty + 8 * i][tx] = h_t[((size_t)b * NPTS + n0 + ty + 8 * i) * CH + o0 + tx];
    __syncthreads();
#pragma unroll
    for (int i = 0; i < 4; ++i) {
        const int o = o0 + ty + 8 * i;
        const float mean = stats[o];
        const float rstd = stats[CH + o];
        const float g = gamma[o], be = beta[o];
        const size_t offp = ((size_t)b * CH + o) * NPTS + n0 + tx;
        out[offp] = x[offp] + g * ((t[tx][ty + 8 * i] - mean) * rstd) + be;
    }
}

// ---------------------------------------------------------------------------
extern "C" void kernel_launch(void* const* d_in, const int* in_sizes, int n_in,
                              void* d_out, int out_size, void* d_ws, size_t ws_size,
                              hipStream_t stream) {
    const float* xyz    = (const float*)d_in[0];
    const float* x      = (const float*)d_in[1];
    const float* conv_w = (const float*)d_in[2];
    const float* conv_b = (const float*)d_in[3];
    const float* gamma  = (const float*)d_in[4];
    const float* beta   = (const float*)d_in[5];
    float* out = (float*)d_out;

    char* ws = (char*)d_ws;
    float*        xt     = (float*)(ws + XT_OFF);
    int*          counts = (int*)  (ws + CNT_OFF);
    int*          cursor = (int*)  (ws + CUR_OFF);
    int2*         hdr    = (int2*) (ws + HDR_OFF);
    unsigned int* occ    = (unsigned int*)(ws + OCC_OFF);
    float4*       spts   = (float4*)(ws + SPTS_OFF);
    int*          gctr   = (int*)  (ws + GCTR_OFF);
    float*        h_t    = (float*)(ws + HT_OFF);
    int*          idx    = (int*)  (ws + IDX_OFF);
    float*        part   = (float*)(ws + PART_OFF);
    float*        stats  = (float*)(ws + STATS_OFF);

    // feature transpose (independent of grid work)
    transpose_kernel<<<dim3(NPTS / 32, CH / 32, BATCH), dim3(32, 8), 0, stream>>>(x, xt);

    // grid build
    zero_kernel<<<dim3(2048), dim3(256), 0, stream>>>(counts, 2 * BATCH * GRID3, gctr);
    count_kernel<<<dim3(NPTS / 256, BATCH), dim3(256), 0, stream>>>(xyz, counts);
    cellhdr_kernel<<<dim3(BATCH * GRID3 / 256), dim3(256), 0, stream>>>(counts, hdr, occ, gctr);
    scatter_kernel<<<dim3(NPTS / 256, BATCH), dim3(256), 0, stream>>>(xyz, hdr, cursor, spts);

    // exact knn
    knn_grid_kernel<<<dim3(NPTS / 256, BATCH), dim3(256), 0, stream>>>(spts, hdr, occ, idx);

    // gather + conv + relu + partial BN sums (overwrites grid region with h_t)
    conv_kernel<<<dim3(BATCH * NPTS / 16), dim3(128), 0, stream>>>(xt, idx, conv_w, conv_b, h_t, part);
    bnred_kernel<<<dim3(CH), dim3(256), 0, stream>>>(part, stats);
    final_kernel<<<dim3(NPTS / 32, CH / 32, BATCH), dim3(32, 8), 0, stream>>>(x, h_t, stats, gamma, beta, out);
}